// Round 8
// baseline (59.791 us; speedup 1.0000x reference)
//
#include <hip/hip_runtime.h>
#include <hip/hip_bf16.h>

typedef __bf16 bf16x8 __attribute__((ext_vector_type(8)));
typedef _Float16 f16x8 __attribute__((ext_vector_type(8)));
typedef _Float16 f16x2 __attribute__((ext_vector_type(2)));
typedef float f32x4 __attribute__((ext_vector_type(4)));

#define B_DIM 16
#define L_DIM 1024
#define H_DIM 4
#define HC 128
#define TI 16

// ---------------------------------------------------------------------------
// Kernel 1 (fused, LDS-free, barrier-free): adjacency bit-pack + projection.
//   Block = 16 rows of B*L, 4 waves; wave w == head w (nc = 2w, 2w+1).
//   Mask: R7's proven coalesced pattern - wave reads 1KB-contiguous int4,
//         lane-local 4-bit pack, shfl_xor 1/2/4 assemble u32 words; 2 passes
//         of 8 int4 (32 VGPR). Diag folded. -> mask_g.
//   Proj: A(W) and B(x) fragments gathered DIRECTLY from global in the
//         verified 16x16x32 fragment layout, cvt to bf16 hi/lo in regs,
//         16 MFMAs/wave. No LDS, no barrier: the 64MB adj stream overlaps
//         the MFMA/cvt compute in one issue stream.
//   Epilogue: xpT f16 store; per-head a_src/a_dst reduce (lane 8-val FMA +
//         shfl_xor 16/32); E1h=f16(16 e^a), E2h=f16(e^{0.2a}), Rr=16 e^{-0.8d}.
// ---------------------------------------------------------------------------
__global__ __launch_bounds__(256) void proj_mask_kernel(
    const float* __restrict__ x, const float* __restrict__ W,
    const float* __restrict__ bias, const float* __restrict__ att_src,
    const float* __restrict__ att_dst, const int* __restrict__ adj,
    _Float16* __restrict__ xpT, _Float16* __restrict__ E1h,
    _Float16* __restrict__ E2h, float* __restrict__ Rr,
    unsigned* __restrict__ mask_g)
{
  const int t = threadIdx.x;
  const int wv = t >> 6, lane = t & 63;
  const int r0g = blockIdx.x * TI;       // global row over B*L
  const int b  = r0g >> 10;
  const int i0 = r0g & 1023;

  const int ln15 = lane & 15;
  const int g8   = (lane >> 4) * 8;
  const int q4   = (lane >> 4) * 4;

  // ---- mask pass 0: issue loads for rows wv*4 + {0,1} ----
  const int grow0 = r0g + wv * 4;
  const int* mbase0 = adj + (size_t)grow0 * L_DIM;
  int4 av[8];
#pragma unroll
  for (int c = 0; c < 4; ++c) {
    av[c]     = *reinterpret_cast<const int4*>(mbase0 + c * 256 + lane * 4);
    av[c + 4] = *reinterpret_cast<const int4*>(mbase0 + 1024 + c * 256 + lane * 4);
  }

  // ---- issue W fragment loads (head wv: n in [wv*32, wv*32+32)) ----
  f32x4 wf32[2][4][2];   // [nc-half][kk][lo/hi quad]
#pragma unroll
  for (int nc = 0; nc < 2; ++nc) {
    const int n = wv * 32 + nc * 16 + ln15;
#pragma unroll
    for (int kk = 0; kk < 4; ++kk) {
      const float* wp = W + (size_t)n * 128 + kk * 32 + g8;
      wf32[nc][kk][0] = *reinterpret_cast<const f32x4*>(wp);
      wf32[nc][kk][1] = *reinterpret_cast<const f32x4*>(wp + 4);
    }
  }
  // ---- issue x fragment loads (col ln15 -> row r0g+ln15) ----
  f32x4 xf32[4][2];
#pragma unroll
  for (int kk = 0; kk < 4; ++kk) {
    const float* xp_ = x + (size_t)(r0g + ln15) * 128 + kk * 32 + g8;
    xf32[kk][0] = *reinterpret_cast<const f32x4*>(xp_);
    xf32[kk][1] = *reinterpret_cast<const f32x4*>(xp_ + 4);
  }

  // ---- pack pass 0 (consumes av; adj pass-1 + W/x still in flight) ----
#pragma unroll
  for (int r = 0; r < 2; ++r) {
    const int row = grow0 + r;
    const int i = row & (L_DIM - 1);
#pragma unroll
    for (int c = 0; c < 4; ++c) {
      const int4 u = av[r * 4 + c];
      unsigned b4 = (unsigned)u.x | ((unsigned)u.y << 1) |
                    ((unsigned)u.z << 2) | ((unsigned)u.w << 3);
      unsigned p;
      p = __shfl_xor(b4, 1);
      unsigned b8  = (lane & 1) ? (p | (b4 << 4))   : (b4 | (p << 4));
      p = __shfl_xor(b8, 2);
      unsigned b16 = (lane & 2) ? (p | (b8 << 8))   : (b8 | (p << 8));
      p = __shfl_xor(b16, 4);
      unsigned b32 = (lane & 4) ? (p | (b16 << 16)) : (b16 | (p << 16));
      const int widx = c * 8 + (lane >> 3);
      if ((i >> 5) == widx) b32 |= (1u << (i & 31));
      if ((lane & 7) == 0) mask_g[(size_t)row * 32 + widx] = b32;
    }
  }

  // ---- mask pass 1: rows wv*4 + {2,3} ----
  const int grow1 = grow0 + 2;
  const int* mbase1 = adj + (size_t)grow1 * L_DIM;
#pragma unroll
  for (int c = 0; c < 4; ++c) {
    av[c]     = *reinterpret_cast<const int4*>(mbase1 + c * 256 + lane * 4);
    av[c + 4] = *reinterpret_cast<const int4*>(mbase1 + 1024 + c * 256 + lane * 4);
  }

  // ---- cvt W/x to bf16 fragments (hi/lo error compensation for x) ----
  bf16x8 wfr[2][4];
#pragma unroll
  for (int nc = 0; nc < 2; ++nc)
#pragma unroll
    for (int kk = 0; kk < 4; ++kk) {
      bf16x8 v;
#pragma unroll
      for (int e = 0; e < 4; ++e) {
        v[e]     = (__bf16)wf32[nc][kk][0][e];
        v[e + 4] = (__bf16)wf32[nc][kk][1][e];
      }
      wfr[nc][kk] = v;
    }
  bf16x8 xhf[4], xlf[4];
#pragma unroll
  for (int kk = 0; kk < 4; ++kk) {
    bf16x8 vh, vl;
#pragma unroll
    for (int e = 0; e < 4; ++e) {
      const float fa = xf32[kk][0][e], fb = xf32[kk][1][e];
      vh[e] = (__bf16)fa;       vh[e + 4] = (__bf16)fb;
      vl[e] = (__bf16)(fa - (float)vh[e]);
      vl[e + 4] = (__bf16)(fb - (float)vh[e + 4]);
    }
    xhf[kk] = vh; xlf[kk] = vl;
  }

  // ---- MFMA core: 2 nc x 4 kk x (hi+lo) = 16 MFMAs (covers adj pass-1) ----
  f32x4 acc0 = {}, acc1 = {};
#pragma unroll
  for (int kk = 0; kk < 4; ++kk) {
    acc0 = __builtin_amdgcn_mfma_f32_16x16x32_bf16(wfr[0][kk], xhf[kk], acc0, 0, 0, 0);
    acc0 = __builtin_amdgcn_mfma_f32_16x16x32_bf16(wfr[0][kk], xlf[kk], acc0, 0, 0, 0);
    acc1 = __builtin_amdgcn_mfma_f32_16x16x32_bf16(wfr[1][kk], xhf[kk], acc1, 0, 0, 0);
    acc1 = __builtin_amdgcn_mfma_f32_16x16x32_bf16(wfr[1][kk], xlf[kk], acc1, 0, 0, 0);
  }

  // ---- pack pass 1 ----
#pragma unroll
  for (int r = 0; r < 2; ++r) {
    const int row = grow1 + r;
    const int i = row & (L_DIM - 1);
#pragma unroll
    for (int c = 0; c < 4; ++c) {
      const int4 u = av[r * 4 + c];
      unsigned b4 = (unsigned)u.x | ((unsigned)u.y << 1) |
                    ((unsigned)u.z << 2) | ((unsigned)u.w << 3);
      unsigned p;
      p = __shfl_xor(b4, 1);
      unsigned b8  = (lane & 1) ? (p | (b4 << 4))   : (b4 | (p << 4));
      p = __shfl_xor(b8, 2);
      unsigned b16 = (lane & 2) ? (p | (b8 << 8))   : (b8 | (p << 8));
      p = __shfl_xor(b16, 4);
      unsigned b32 = (lane & 4) ? (p | (b16 << 16)) : (b16 | (p << 16));
      const int widx = c * 8 + (lane >> 3);
      if ((i >> 5) == widx) b32 |= (1u << (i & 31));
      if ((lane & 7) == 0) mask_g[(size_t)row * 32 + widx] = b32;
    }
  }

  // ---- epilogue: D col=ln15 -> row r0g+ln15; row=q4+reg -> n-offset ----
  float asum = 0.f, adsum = 0.f;
  const int lg = i0 + ln15;
#pragma unroll
  for (int nc = 0; nc < 2; ++nc) {
    const int n0 = wv * 32 + nc * 16 + q4;
    const f32x4 bv = *reinterpret_cast<const f32x4*>(bias + n0);
    const f32x4 sv = *reinterpret_cast<const f32x4*>(att_src + n0);
    const f32x4 dv = *reinterpret_cast<const f32x4*>(att_dst + n0);
    const f32x4 a = nc ? acc1 : acc0;
#pragma unroll
    for (int reg = 0; reg < 4; ++reg) {
      const float v = a[reg] + bv[reg];
      xpT[((size_t)(b * 128 + n0 + reg)) * 1024 + lg] = (_Float16)v;
      asum  = fmaf(v, sv[reg], asum);
      adsum = fmaf(v, dv[reg], adsum);
    }
  }
  asum  += __shfl_xor(asum, 16);
  asum  += __shfl_xor(asum, 32);
  adsum += __shfl_xor(adsum, 16);
  adsum += __shfl_xor(adsum, 32);
  if ((lane >> 4) == 0) {
    const size_t o = ((size_t)(b * H_DIM + wv)) * 1024 + lg;
    E1h[o] = (_Float16)(16.0f * __expf(asum));
    E2h[o] = (_Float16)__expf(0.2f * asum);
    Rr[o]  = 16.0f * __expf(-0.8f * adsum);
  }
}

// ---------------------------------------------------------------------------
// Kernel 2 (flash attn, packed fp16 inner loop; R7 + e-read pipelining):
//   P' = max(16e1, e2*16R) masked via v_pk_mul/v_pk_max_f16 + byte->halfmask
//   LUT; 3 f16 MFMAs/iter. e1/e2 ds_reads now 1 iter ahead (like the LUT).
// ---------------------------------------------------------------------------
__global__ __launch_bounds__(256) void gat_attn_kernel(
    const unsigned* __restrict__ mask_g, const _Float16* __restrict__ xpT,
    const _Float16* __restrict__ E1h, const _Float16* __restrict__ E2h,
    const float* __restrict__ Rr, float* __restrict__ out)
{
  __shared__ __align__(16) unsigned e1u[H_DIM][512];
  __shared__ __align__(16) unsigned e2u[H_DIM][512];
  __shared__ __align__(16) uint4 lutlds[4][257];
  __shared__ __align__(16) unsigned char msk_b[TI][176];

  const int wg  = blockIdx.x;
  const int xcd = wg & 7;
  const int idx = wg >> 3;
  const int b   = xcd * 2 + (idx & 1);
  const int i0  = (idx >> 1) * TI;

  const int t = threadIdx.x;
  const int wv = t >> 6;
  const int lane = t & 63;

  {
    const unsigned m0 = ((t & 1) ? 0xFFFFu : 0u) | ((t & 2) ? 0xFFFF0000u : 0u);
    const unsigned m1 = ((t & 4) ? 0xFFFFu : 0u) | ((t & 8) ? 0xFFFF0000u : 0u);
    const unsigned m2 = ((t & 16) ? 0xFFFFu : 0u) | ((t & 32) ? 0xFFFF0000u : 0u);
    const unsigned m3 = ((t & 64) ? 0xFFFFu : 0u) | ((t & 128) ? 0xFFFF0000u : 0u);
    const uint4 ent = {m0, m1, m2, m3};
#pragma unroll
    for (int q = 0; q < 4; ++q) lutlds[q][t] = ent;
  }
  {
    const int r = t >> 4, sg = t & 15;
    const uint2 m = *reinterpret_cast<const uint2*>(
        mask_g + ((size_t)b * L_DIM + i0 + r) * 32 + sg * 2);
    *reinterpret_cast<uint2*>(&msk_b[r][sg * 8]) = m;
  }
  {
    const unsigned* p1 = reinterpret_cast<const unsigned*>(E1h + ((size_t)(b * H_DIM + wv)) * L_DIM);
    const unsigned* p2 = reinterpret_cast<const unsigned*>(E2h + ((size_t)(b * H_DIM + wv)) * L_DIM);
#pragma unroll
    for (int it = 0; it < 2; ++it) {
      const int ix = it * 256 + lane * 4;
      *reinterpret_cast<uint4*>(&e1u[wv][ix]) = *reinterpret_cast<const uint4*>(p1 + ix);
      *reinterpret_cast<uint4*>(&e2u[wv][ix]) = *reinterpret_cast<const uint4*>(p2 + ix);
    }
  }
  __syncthreads();

  const int h = wv;
  const int ln15 = lane & 15;
  const int kh = lane >> 4;
  const int jb = kh * 8;
  const int lq = lane >> 4;
  const float Rrow = Rr[((size_t)(b * H_DIM + h)) * L_DIM + i0 + ln15];
  const _Float16 rh = (_Float16)Rrow;
  const f16x2 R2 = {rh, rh};
  const _Float16* xb0 = xpT + ((size_t)(b * 128 + h * 32 + ln15)) * 1024;
  const _Float16* xb1 = xb0 + 16 * 1024;

  f32x4 acc0 = {0.f, 0.f, 0.f, 0.f};
  f32x4 acc1 = {0.f, 0.f, 0.f, 0.f};
  f32x4 accS = {0.f, 0.f, 0.f, 0.f};
  f16x8 ones16;
#pragma unroll
  for (int e = 0; e < 8; ++e) ones16[e] = (_Float16)1.0f;

  uint4 pf0[4], pf1[4];
#pragma unroll
  for (int s = 0; s < 4; ++s) {
    pf0[s] = *reinterpret_cast<const uint4*>(xb0 + s * 32 + jb);
    pf1[s] = *reinterpret_cast<const uint4*>(xb1 + s * 32 + jb);
  }

  uint4 mw_pf = *reinterpret_cast<const uint4*>(&msk_b[ln15][0]);
  uint4 mwc = mw_pf;
  uint4 lutv = lutlds[lq][(mw_pf.x >> (kh * 8)) & 0xffu];
  // e-read software pipeline: current values pre-loaded
  uint4 u1c = *reinterpret_cast<const uint4*>(&e1u[h][jb >> 1]);
  uint4 u2c = *reinterpret_cast<const uint4*>(&e2u[h][jb >> 1]);

#pragma unroll 4
  for (int k0 = 0; k0 < L_DIM; k0 += 32) {
    const int tm = (k0 >> 5) & 3;
    if (tm == 0) {
      mwc = mw_pf;
      if (k0 < 896)
        mw_pf = *reinterpret_cast<const uint4*>(&msk_b[ln15][(k0 >> 7) * 16 + 16]);
    }
    unsigned mb_n;
    if (tm == 0)      mb_n = (mwc.y >> (kh * 8)) & 0xffu;
    else if (tm == 1) mb_n = (mwc.z >> (kh * 8)) & 0xffu;
    else if (tm == 2) mb_n = (mwc.w >> (kh * 8)) & 0xffu;
    else              mb_n = (mw_pf.x >> (kh * 8)) & 0xffu;
    const uint4 lutv_n = lutlds[lq][mb_n];

    // next-iter e-reads (wrap at end; wrapped value never consumed)
    const int kn = (((k0 + 32) & 1023) + jb) >> 1;
    const uint4 u1n = *reinterpret_cast<const uint4*>(&e1u[h][kn]);
    const uint4 u2n = *reinterpret_cast<const uint4*>(&e2u[h][kn]);

    const uint4 bb0 = pf0[tm];
    const uint4 bb1 = pf1[tm];
    pf0[tm] = *reinterpret_cast<const uint4*>(xb0 + k0 + 128 + jb);  // over-read lands in ws
    pf1[tm] = *reinterpret_cast<const uint4*>(xb1 + k0 + 128 + jb);

    const unsigned uu1[4] = {u1c.x, u1c.y, u1c.z, u1c.w};
    const unsigned uu2[4] = {u2c.x, u2c.y, u2c.z, u2c.w};
    const unsigned ll[4]  = {lutv.x, lutv.y, lutv.z, lutv.w};
    unsigned rr4[4];
#pragma unroll
    for (int q = 0; q < 4; ++q) {
      f16x2 a, ee;
      __builtin_memcpy(&a,  &uu1[q], 4);
      __builtin_memcpy(&ee, &uu2[q], 4);
      const f16x2 pr = ee * R2;                            // v_pk_mul_f16
      const f16x2 mx = __builtin_elementwise_max(a, pr);   // v_pk_max_f16
      unsigned mu;
      __builtin_memcpy(&mu, &mx, 4);
      rr4[q] = mu & ll[q];
    }
    const uint4 afu = {rr4[0], rr4[1], rr4[2], rr4[3]};
    f16x8 af, b0h, b1h;
    __builtin_memcpy(&af,  &afu, 16);
    __builtin_memcpy(&b0h, &bb0, 16);
    __builtin_memcpy(&b1h, &bb1, 16);
    acc0 = __builtin_amdgcn_mfma_f32_16x16x32_f16(af, b0h, acc0, 0, 0, 0);
    acc1 = __builtin_amdgcn_mfma_f32_16x16x32_f16(af, b1h, acc1, 0, 0, 0);
    accS = __builtin_amdgcn_mfma_f32_16x16x32_f16(af, ones16, accS, 0, 0, 0);
    lutv = lutv_n;
    u1c = u1n; u2c = u2n;
  }

#pragma unroll
  for (int reg = 0; reg < 4; ++reg) {
    const float rs = 1.0f / accS[reg];
    float* op = out + ((size_t)(b * L_DIM + i0 + kh * 4 + reg)) * HC + h * 32;
    op[ln15]      = acc0[reg] * rs;
    op[16 + ln15] = acc1[reg] * rs;
  }
}

extern "C" void kernel_launch(void* const* d_in, const int* in_sizes, int n_in,
                              void* d_out, int out_size, void* d_ws, size_t ws_size,
                              hipStream_t stream) {
  (void)in_sizes; (void)n_in; (void)out_size; (void)ws_size;
  const float* x        = (const float*)d_in[0];
  const int*   adj      = (const int*)d_in[1];
  const float* W        = (const float*)d_in[2];
  const float* bias     = (const float*)d_in[3];
  const float* att_src  = (const float*)d_in[4];
  const float* att_dst  = (const float*)d_in[5];
  float* out = (float*)d_out;

  char* ws = (char*)d_ws;
  _Float16* xpT    = (_Float16*)ws;                                    // 4 MiB
  _Float16* E1h    = (_Float16*)(ws + (size_t)4 * 1024 * 1024);        // 128 KiB
  _Float16* E2h    = (_Float16*)(ws + (size_t)4 * 1024 * 1024 + 131072);
  float*    Rr     = (float*)(ws + (size_t)4 * 1024 * 1024 + 262144);  // 256 KiB
  unsigned* mask_g = (unsigned*)(ws + (size_t)4 * 1024 * 1024 + 524288); // 2 MiB

  hipLaunchKernelGGL(proj_mask_kernel, dim3(B_DIM * L_DIM / TI), dim3(256), 0, stream,
                     x, W, bias, att_src, att_dst, adj, xpT, E1h, E2h, Rr, mask_g);
  hipLaunchKernelGGL(gat_attn_kernel, dim3(B_DIM * L_DIM / TI), dim3(256), 0, stream,
                     mask_g, xpT, E1h, E2h, Rr, out);
}

// Round 9
// 58.577 us; speedup vs baseline: 1.0207x; 1.0207x over previous
//
#include <hip/hip_runtime.h>
#include <hip/hip_bf16.h>

typedef __bf16 bf16x8 __attribute__((ext_vector_type(8)));
typedef _Float16 f16x8 __attribute__((ext_vector_type(8)));
typedef _Float16 f16x2 __attribute__((ext_vector_type(2)));
typedef float f32x4 __attribute__((ext_vector_type(4)));

#define B_DIM 16
#define L_DIM 1024
#define H_DIM 4
#define HC 128
#define TI 16
#define WPITCH 136   // bf16 elems; 272B rows, 16B-aligned

// ---------------------------------------------------------------------------
// Kernel 1: adjacency -> packed bitmask (R7, proven). COALESCED: lane l reads
// 16B at base + l*16 (one wave-load = 1KB contiguous). Lane-local 4-bit pack,
// shfl_xor 1/2/4 assemble u32 words. Diag folded.
// ---------------------------------------------------------------------------
__global__ __launch_bounds__(256) void mask_pack_kernel(
    const int* __restrict__ adj, unsigned* __restrict__ mask_g)
{
  const int t = threadIdx.x;
  const int wv = t >> 6, lane = t & 63;
  const int row0 = blockIdx.x * 8 + wv * 2;
  const int* base = adj + (size_t)row0 * L_DIM;

  int4 av[8];
#pragma unroll
  for (int c = 0; c < 4; ++c) {
    av[c]     = *reinterpret_cast<const int4*>(base + c * 256 + lane * 4);
    av[c + 4] = *reinterpret_cast<const int4*>(base + 1024 + c * 256 + lane * 4);
  }

#pragma unroll
  for (int r = 0; r < 2; ++r) {
    const int row = row0 + r;
    const int i = row & (L_DIM - 1);
#pragma unroll
    for (int c = 0; c < 4; ++c) {
      const int4 u = av[r * 4 + c];
      unsigned b4 = (unsigned)u.x | ((unsigned)u.y << 1) |
                    ((unsigned)u.z << 2) | ((unsigned)u.w << 3);
      unsigned p;
      p = __shfl_xor(b4, 1);
      unsigned b8  = (lane & 1) ? (p | (b4 << 4))   : (b4 | (p << 4));
      p = __shfl_xor(b8, 2);
      unsigned b16 = (lane & 2) ? (p | (b8 << 8))   : (b8 | (p << 8));
      p = __shfl_xor(b16, 4);
      unsigned b32 = (lane & 4) ? (p | (b16 << 16)) : (b16 | (p << 16));
      const int widx = c * 8 + (lane >> 3);
      if ((i >> 5) == widx) b32 |= (1u << (i & 31));
      if ((lane & 7) == 0) mask_g[(size_t)row * 32 + widx] = b32;
    }
  }
}

// ---------------------------------------------------------------------------
// Kernel 2: projection via MFMA (R7, proven). bf16 hi/lo error-compensated
// core; fp16 outputs xpT/E1h/E2h; Rr f32. x16 pre-scale for fp16 range.
// ---------------------------------------------------------------------------
__global__ __launch_bounds__(128) void proj_kernel(
    const float* __restrict__ x, const float* __restrict__ W,
    const float* __restrict__ bias, const float* __restrict__ att_src,
    const float* __restrict__ att_dst, _Float16* __restrict__ xpT,
    _Float16* __restrict__ E1h, _Float16* __restrict__ E2h,
    float* __restrict__ Rr)
{
  __shared__ __align__(16) __bf16 Wlds[128 * WPITCH];
  __shared__ __align__(16) __bf16 xh[32 * WPITCH];
  __shared__ __align__(16) __bf16 xl[32 * WPITCH];
  const int t = threadIdx.x;
  const int w = t >> 6;
  const int lane = t & 63;
  const int r0 = blockIdx.x * 32;

#pragma unroll
  for (int p = 0; p < 16; ++p) {
    const int idx = p * 1024 + t * 8;
    const int n = idx >> 7, k = idx & 127;
    const f32x4 a = *reinterpret_cast<const f32x4*>(W + idx);
    const f32x4 b = *reinterpret_cast<const f32x4*>(W + idx + 4);
    bf16x8 v;
#pragma unroll
    for (int e = 0; e < 4; ++e) { v[e] = (__bf16)a[e]; v[e + 4] = (__bf16)b[e]; }
    *reinterpret_cast<bf16x8*>(&Wlds[n * WPITCH + k]) = v;
  }
#pragma unroll
  for (int p = 0; p < 4; ++p) {
    const int idx = p * 1024 + t * 8;
    const int r = idx >> 7, k = idx & 127;
    const float* xp_ = x + (size_t)(r0 + r) * 128 + k;
    const f32x4 a = *reinterpret_cast<const f32x4*>(xp_);
    const f32x4 b = *reinterpret_cast<const f32x4*>(xp_ + 4);
    bf16x8 vh, vl;
#pragma unroll
    for (int e = 0; e < 4; ++e) {
      const float fa = a[e], fb = b[e];
      vh[e] = (__bf16)fa;          vh[e + 4] = (__bf16)fb;
      vl[e] = (__bf16)(fa - (float)vh[e]);
      vl[e + 4] = (__bf16)(fb - (float)vh[e + 4]);
    }
    *reinterpret_cast<bf16x8*>(&xh[r * WPITCH + k]) = vh;
    *reinterpret_cast<bf16x8*>(&xl[r * WPITCH + k]) = vl;
  }
  __syncthreads();

  const int rr = lane & 15;
  const int g8 = (lane >> 4) * 8;
  f32x4 acc[8] = {};
#pragma unroll
  for (int kk = 0; kk < 4; ++kk) {
    const int ko = kk * 32 + g8;
    const bf16x8 bh = *reinterpret_cast<const bf16x8*>(&xh[(w * 16 + rr) * WPITCH + ko]);
    const bf16x8 bl = *reinterpret_cast<const bf16x8*>(&xl[(w * 16 + rr) * WPITCH + ko]);
#pragma unroll
    for (int nc = 0; nc < 8; ++nc) {
      const bf16x8 af = *reinterpret_cast<const bf16x8*>(&Wlds[(nc * 16 + rr) * WPITCH + ko]);
      acc[nc] = __builtin_amdgcn_mfma_f32_16x16x32_bf16(af, bh, acc[nc], 0, 0, 0);
      acc[nc] = __builtin_amdgcn_mfma_f32_16x16x32_bf16(af, bl, acc[nc], 0, 0, 0);
    }
  }

  const int q4 = (lane >> 4) * 4;
  const int grow = r0 + w * 16 + rr;
  const int bb = grow >> 10;
  const int lg = grow & 1023;
  float asum[4] = {0.f, 0.f, 0.f, 0.f};
  float adsum[4] = {0.f, 0.f, 0.f, 0.f};
#pragma unroll
  for (int nc = 0; nc < 8; ++nc) {
    const int n0 = nc * 16 + q4;
    const f32x4 bv = *reinterpret_cast<const f32x4*>(bias + n0);
    const f32x4 sv = *reinterpret_cast<const f32x4*>(att_src + n0);
    const f32x4 dv = *reinterpret_cast<const f32x4*>(att_dst + n0);
    const int h = nc >> 1;
#pragma unroll
    for (int reg = 0; reg < 4; ++reg) {
      const float v = acc[nc][reg] + bv[reg];
      const int n = n0 + reg;
      xpT[((size_t)bb * 128 + n) * 1024 + lg] = (_Float16)v;
      asum[h]  = fmaf(v, sv[reg], asum[h]);
      adsum[h] = fmaf(v, dv[reg], adsum[h]);
    }
  }
#pragma unroll
  for (int h = 0; h < 4; ++h) {
    asum[h]  += __shfl_xor(asum[h], 16);
    asum[h]  += __shfl_xor(asum[h], 32);
    adsum[h] += __shfl_xor(adsum[h], 16);
    adsum[h] += __shfl_xor(adsum[h], 32);
  }
  if ((lane >> 4) == 0) {
#pragma unroll
    for (int h = 0; h < 4; ++h) {
      const size_t o = ((size_t)bb * 4 + h) * 1024 + lg;
      E1h[o] = (_Float16)(16.0f * __expf(asum[h]));
      E2h[o] = (_Float16)__expf(0.2f * asum[h]);
      Rr[o]  = 16.0f * __expf(-0.8f * adsum[h]);
    }
  }
}

// ---------------------------------------------------------------------------
// Kernel 3 (flash attn, fp16 packed, NO LUT):
//   Mask bits expanded to halfword masks in pure VALU (cmp+cndmask) - no
//   LDS gather, no conflicts, no LDS dependency in the chain. LDS ~19.2KB
//   -> 8 blocks/CU (32 waves/CU) with __launch_bounds__(256,8).
//   P' = max(16e1, e2*16R) & mask via v_pk_mul/v_pk_max; 3 f16 MFMAs/iter;
//   e-reads pipelined 1 iter; 4-deep xpT ring; lane-local normalize.
// ---------------------------------------------------------------------------
__global__ __launch_bounds__(256, 8) void gat_attn_kernel(
    const unsigned* __restrict__ mask_g, const _Float16* __restrict__ xpT,
    const _Float16* __restrict__ E1h, const _Float16* __restrict__ E2h,
    const float* __restrict__ Rr, float* __restrict__ out)
{
  __shared__ __align__(16) unsigned e1u[H_DIM][512];    // 8 KB
  __shared__ __align__(16) unsigned e2u[H_DIM][512];    // 8 KB
  __shared__ __align__(16) unsigned char msk_b[TI][176]; // 2.75 KB

  const int wg  = blockIdx.x;
  const int xcd = wg & 7;
  const int idx = wg >> 3;
  const int b   = xcd * 2 + (idx & 1);
  const int i0  = (idx >> 1) * TI;

  const int t = threadIdx.x;
  const int wv = t >> 6;
  const int lane = t & 63;

  {
    const int r = t >> 4, sg = t & 15;
    const uint2 m = *reinterpret_cast<const uint2*>(
        mask_g + ((size_t)b * L_DIM + i0 + r) * 32 + sg * 2);
    *reinterpret_cast<uint2*>(&msk_b[r][sg * 8]) = m;
  }
  {
    const unsigned* p1 = reinterpret_cast<const unsigned*>(E1h + ((size_t)(b * H_DIM + wv)) * L_DIM);
    const unsigned* p2 = reinterpret_cast<const unsigned*>(E2h + ((size_t)(b * H_DIM + wv)) * L_DIM);
#pragma unroll
    for (int it = 0; it < 2; ++it) {
      const int ix = it * 256 + lane * 4;
      *reinterpret_cast<uint4*>(&e1u[wv][ix]) = *reinterpret_cast<const uint4*>(p1 + ix);
      *reinterpret_cast<uint4*>(&e2u[wv][ix]) = *reinterpret_cast<const uint4*>(p2 + ix);
    }
  }
  __syncthreads();

  const int h = wv;
  const int ln15 = lane & 15;
  const int kh = lane >> 4;
  const int jb = kh * 8;
  const float Rrow = Rr[((size_t)(b * H_DIM + h)) * L_DIM + i0 + ln15];
  const _Float16 rh = (_Float16)Rrow;
  const f16x2 R2 = {rh, rh};
  const _Float16* xb0 = xpT + ((size_t)(b * 128 + h * 32 + ln15)) * 1024;
  const _Float16* xb1 = xb0 + 16 * 1024;

  f32x4 acc0 = {0.f, 0.f, 0.f, 0.f};
  f32x4 acc1 = {0.f, 0.f, 0.f, 0.f};
  f32x4 accS = {0.f, 0.f, 0.f, 0.f};
  f16x8 ones16;
#pragma unroll
  for (int e = 0; e < 8; ++e) ones16[e] = (_Float16)1.0f;

  uint4 pf0[4], pf1[4];
#pragma unroll
  for (int s = 0; s < 4; ++s) {
    pf0[s] = *reinterpret_cast<const uint4*>(xb0 + s * 32 + jb);
    pf1[s] = *reinterpret_cast<const uint4*>(xb1 + s * 32 + jb);
  }

  uint4 mw_pf = *reinterpret_cast<const uint4*>(&msk_b[ln15][0]);
  uint4 mwc = mw_pf;
  // e-read software pipeline: current values pre-loaded
  uint4 u1c = *reinterpret_cast<const uint4*>(&e1u[h][jb >> 1]);
  uint4 u2c = *reinterpret_cast<const uint4*>(&e2u[h][jb >> 1]);

#pragma unroll 4
  for (int k0 = 0; k0 < L_DIM; k0 += 32) {
    const int tm = (k0 >> 5) & 3;
    if (tm == 0) {
      mwc = mw_pf;
      if (k0 < 896)
        mw_pf = *reinterpret_cast<const uint4*>(&msk_b[ln15][(k0 >> 7) * 16 + 16]);
    }
    const unsigned word = (tm == 0) ? mwc.x : (tm == 1) ? mwc.y
                        : (tm == 2) ? mwc.z : mwc.w;
    const unsigned mb = (word >> (kh * 8)) & 0xffu;

    // next-iter e-reads (wrap at end; wrapped value never consumed)
    const int kn = (((k0 + 32) & 1023) + jb) >> 1;
    const uint4 u1n = *reinterpret_cast<const uint4*>(&e1u[h][kn]);
    const uint4 u2n = *reinterpret_cast<const uint4*>(&e2u[h][kn]);

    const uint4 bb0 = pf0[tm];
    const uint4 bb1 = pf1[tm];
    pf0[tm] = *reinterpret_cast<const uint4*>(xb0 + k0 + 128 + jb);  // over-read lands in ws
    pf1[tm] = *reinterpret_cast<const uint4*>(xb1 + k0 + 128 + jb);

    const unsigned uu1[4] = {u1c.x, u1c.y, u1c.z, u1c.w};
    const unsigned uu2[4] = {u2c.x, u2c.y, u2c.z, u2c.w};
    unsigned rr4[4];
#pragma unroll
    for (int q = 0; q < 4; ++q) {
      f16x2 a, ee;
      __builtin_memcpy(&a,  &uu1[q], 4);
      __builtin_memcpy(&ee, &uu2[q], 4);
      const f16x2 pr = ee * R2;                            // v_pk_mul_f16
      const f16x2 mx = __builtin_elementwise_max(a, pr);   // v_pk_max_f16
      unsigned mu;
      __builtin_memcpy(&mu, &mx, 4);
      // VALU mask expansion: 2 bits -> halfword masks (cmp+cndmask each)
      const unsigned mlo = (mb & (1u << (2 * q)))     ? 0xFFFFu : 0u;
      const unsigned mhi = (mb & (1u << (2 * q + 1))) ? 0xFFFF0000u : 0u;
      rr4[q] = mu & (mlo | mhi);
    }
    const uint4 afu = {rr4[0], rr4[1], rr4[2], rr4[3]};
    f16x8 af, b0h, b1h;
    __builtin_memcpy(&af,  &afu, 16);
    __builtin_memcpy(&b0h, &bb0, 16);
    __builtin_memcpy(&b1h, &bb1, 16);
    acc0 = __builtin_amdgcn_mfma_f32_16x16x32_f16(af, b0h, acc0, 0, 0, 0);
    acc1 = __builtin_amdgcn_mfma_f32_16x16x32_f16(af, b1h, acc1, 0, 0, 0);
    accS = __builtin_amdgcn_mfma_f32_16x16x32_f16(af, ones16, accS, 0, 0, 0);
    u1c = u1n; u2c = u2n;
  }

#pragma unroll
  for (int reg = 0; reg < 4; ++reg) {
    const float rs = 1.0f / accS[reg];
    float* op = out + ((size_t)(b * L_DIM + i0 + kh * 4 + reg)) * HC + h * 32;
    op[ln15]      = acc0[reg] * rs;
    op[16 + ln15] = acc1[reg] * rs;
  }
}

extern "C" void kernel_launch(void* const* d_in, const int* in_sizes, int n_in,
                              void* d_out, int out_size, void* d_ws, size_t ws_size,
                              hipStream_t stream) {
  (void)in_sizes; (void)n_in; (void)out_size; (void)ws_size;
  const float* x        = (const float*)d_in[0];
  const int*   adj      = (const int*)d_in[1];
  const float* W        = (const float*)d_in[2];
  const float* bias     = (const float*)d_in[3];
  const float* att_src  = (const float*)d_in[4];
  const float* att_dst  = (const float*)d_in[5];
  float* out = (float*)d_out;

  char* ws = (char*)d_ws;
  _Float16* xpT    = (_Float16*)ws;                                    // 4 MiB
  _Float16* E1h    = (_Float16*)(ws + (size_t)4 * 1024 * 1024);        // 128 KiB
  _Float16* E2h    = (_Float16*)(ws + (size_t)4 * 1024 * 1024 + 131072);
  float*    Rr     = (float*)(ws + (size_t)4 * 1024 * 1024 + 262144);  // 256 KiB
  unsigned* mask_g = (unsigned*)(ws + (size_t)4 * 1024 * 1024 + 524288); // 2 MiB

  hipLaunchKernelGGL(mask_pack_kernel, dim3(B_DIM * L_DIM / 8), dim3(256), 0, stream,
                     adj, mask_g);
  hipLaunchKernelGGL(proj_kernel, dim3(B_DIM * L_DIM / 32), dim3(128), 0, stream,
                     x, W, bias, att_src, att_dst, xpT, E1h, E2h, Rr);
  hipLaunchKernelGGL(gat_attn_kernel, dim3(B_DIM * L_DIM / TI), dim3(256), 0, stream,
                     mask_g, xpT, E1h, E2h, Rr, out);
}